// Round 11
// baseline (305.801 us; speedup 1.0000x reference)
//
#include <hip/hip_runtime.h>
#include <math.h>

// Problem constants
#define BB 16
#define HH 64
#define LL 16384
#define NST 32
#define LC 256
#define CC 64              // LL/LC
#define BL (BB*LL)         // 262144

typedef _Float16 f16;
typedef f16  f16x8 __attribute__((ext_vector_type(8)));
typedef float f32x4 __attribute__((ext_vector_type(4)));

// ws layout (float offsets). Total ~71.4 MB.
// NOTE: y1 is written IN PLACE over OFF_H by gemmMain (each (ch,col) owned by
// exactly one block; gemmA, the only other H reader, runs before it).
// NOTE: OFF_P is reused three times: kprep writes Kl[64][256] (first 16K
// floats), gemmA overwrites all of P, k_cm2s reuses it for BN partials.
// NOTE: y2 is NEVER materialized — k_cm2s computes stats from registers;
// k6m recomputes the bit-identical y2 and applies BN/FiLM/PReLU/residual.
#define OFF_H   ((size_t)0)            // h f16 -> later y1 f16: 16,777,216 halves
#define OFF_P   ((size_t)8388608)      // P fp32: 64ch x 64row x 1024col; Kl; BN partials
#define OFF_S   ((size_t)12582912)     // S_t f16: [ch][1024 col][64 row]
#define OFF_T   ((size_t)14680064)     // T f16: [ch][256][256]
#define OFF_V   ((size_t)16777216)     // V f16: [ch][64][256]
#define OFF_U   ((size_t)17301504)     // U f16: [ch][256][64]
#define OFF_PW  ((size_t)17825792)     // per-state params float4 x 2048
#define OFF_WL  ((size_t)17833984)     // w^Lc: float2 x 2048
#define OFF_GB  ((size_t)17838080)     // FiLM gamma/beta: 2048
#define OFF_BN  ((size_t)17840128)     // (unused now)
#define OFF_BNF ((size_t)17840256)     // BN mean/inv: 128

// ---------------------------------------------------------------------------
// K0: derived S4D params (w, 2*Cd, w^Lc), FiLM gamma/beta.
// ---------------------------------------------------------------------------
__global__ void k0_setup(const float* __restrict__ log_dt,
                         const float* __restrict__ log_A_real,
                         const float* __restrict__ A_imag,
                         const float* __restrict__ C_re,
                         const float* __restrict__ C_im,
                         const float* __restrict__ cond,
                         const float* __restrict__ film_w,
                         const float* __restrict__ film_b,
                         float* __restrict__ ws) {
    int t = threadIdx.x, bid = blockIdx.x;
    if (bid < 8) {
        float4* pw = (float4*)(ws + OFF_PW);
        float2* wl = (float2*)(ws + OFF_WL);
        int idx = bid * 256 + t;             // state index = ch*32 + n
        int ch = idx >> 5;
        float dt  = expf(log_dt[ch]);
        float are = -expf(log_A_real[idx]);
        float aim = A_imag[idx];
        float dr = are * dt, di = aim * dt;
        float er = expf(dr);
        float wr = er * cosf(di);
        float wi = er * sinf(di);
        float inv = 1.0f / (are * are + aim * aim);
        float gr = ((wr - 1.0f) * are + wi * aim) * inv;
        float gi = (wi * are - (wr - 1.0f) * aim) * inv;
        float cr = C_re[idx], ci = C_im[idx];
        float cdr = cr * gr - ci * gi;
        float cdi = cr * gi + ci * gr;
        pw[idx] = make_float4(wr, wi, 2.0f * cdr, 2.0f * cdi);
        float erL = expf(dr * (float)LC);
        wl[idx] = make_float2(erL * cosf(di * (float)LC), erL * sinf(di * (float)LC));
    } else {
        float* gb = ws + OFF_GB;
        int o = (bid - 8) * 256 + t;         // o = b*128 + j
        int b = o >> 7, j = o & 127;
        float acc = film_b[j];
        for (int q = 0; q < 128; q++)
            acc = fmaf(cond[b * 128 + q], film_w[j * 128 + q], acc);
        gb[o] = acc;
    }
}

// ---------------------------------------------------------------------------
// KPREP: Kl[ch][d] = sum_n Re(2Cd_n * w_n^d)  (+Dskip at d==0).
// grid 64. Written to the P region (dead until gemmA overwrites it).
// ---------------------------------------------------------------------------
__global__ __launch_bounds__(256) void kprep(const float* __restrict__ log_dt,
                                             const float* __restrict__ log_A,
                                             const float* __restrict__ A_imag,
                                             const float* __restrict__ Dskip,
                                             float* __restrict__ ws) {
    __shared__ float drs[32], dis[32], c2r[32], c2i[32];
    int ch = blockIdx.x, t = threadIdx.x;
    if (t < 32) {
        float dt = expf(log_dt[ch]);
        float are = -expf(log_A[ch * 32 + t]);
        float aim = A_imag[ch * 32 + t];
        drs[t] = are * dt; dis[t] = aim * dt;
        float4 p = ((const float4*)(ws + OFF_PW))[ch * 32 + t];
        c2r[t] = p.z; c2i[t] = p.w;
    }
    __syncthreads();
    float acc = 0.0f;
    float fd = (float)t;
    for (int n = 0; n < 32; n++) {
        float e = expf(drs[n] * fd);
        float ph = dis[n] * fd;
        acc += c2r[n] * e * cosf(ph) - c2i[n] * e * sinf(ph);
    }
    if (t == 0) acc += Dskip[ch];
    ws[OFF_P + (size_t)ch * 256 + t] = acc;
}

// ---------------------------------------------------------------------------
// KBUILD v3: per-channel f16 matrices from precomputed Kl.
// grid 1024 = 64 ch x 16 parts.
// ---------------------------------------------------------------------------
__global__ __launch_bounds__(256) void kbuild(const float* __restrict__ log_dt,
                                              const float* __restrict__ log_A,
                                              const float* __restrict__ A_imag,
                                              float* __restrict__ ws) {
    __shared__ float Kl[256];
    __shared__ float drs[32], dis[32], c2r[32], c2i[32];
    int bid = blockIdx.x;
    int ch = bid >> 4, part = bid & 15;
    int t = threadIdx.x;
    if (t < 32) {
        float dt = expf(log_dt[ch]);
        float are = -expf(log_A[ch * 32 + t]);
        float aim = A_imag[ch * 32 + t];
        drs[t] = are * dt; dis[t] = aim * dt;
        float4 p = ((const float4*)(ws + OFF_PW))[ch * 32 + t];
        c2r[t] = p.z; c2i[t] = p.w;
    }
    Kl[t] = ws[OFF_P + (size_t)ch * 256 + t];
    __syncthreads();
    f16* T = (f16*)(ws + OFF_T) + (size_t)ch * 65536;
    {
        int r0 = part * 16;
#pragma unroll
        for (int i = 0; i < 2; i++) {
            int idx = t + i * 256;
            int row = r0 + (idx >> 5);
            int c0 = (idx & 31) * 8;
            f16 vals[8];
#pragma unroll
            for (int j = 0; j < 8; j++) {
                int c = c0 + j;
                vals[j] = (f16)((c <= row) ? Kl[row - c] : 0.0f);
            }
            *(float4*)(T + (size_t)row * 256 + c0) = *(const float4*)vals;
        }
    }
    if (part < 8) {
        f16* V = (f16*)(ws + OFF_V) + (size_t)ch * 16384;
        int row = part * 8 + (t >> 5);
        int c0 = (t & 31) * 8;
        int n = row & 31;
        f16 vals[8];
#pragma unroll
        for (int j = 0; j < 8; j++) {
            float fe = (float)(255 - (c0 + j));
            float e = expf(drs[n] * fe);
            float ph = dis[n] * fe;
            vals[j] = (f16)((row < 32) ? e * cosf(ph) : e * sinf(ph));
        }
        *(float4*)(V + (size_t)row * 256 + c0) = *(const float4*)vals;
    } else {
        f16* U = (f16*)(ws + OFF_U) + (size_t)ch * 16384;
        int l = (part - 8) * 32 + (t >> 3);
        int c0 = (t & 7) * 8;
        float fl1 = (float)(l + 1);
        f16 vals[8];
#pragma unroll
        for (int nn = 0; nn < 4; nn++) {
            int n = (c0 >> 1) + nn;
            float e = expf(drs[n] * fl1);
            float ph = dis[n] * fl1;
            float wre = e * cosf(ph), wim = e * sinf(ph);
            float re = c2r[n] * wre - c2i[n] * wim;
            float im = c2r[n] * wim + c2i[n] * wre;
            vals[2 * nn]     = (f16)re;
            vals[2 * nn + 1] = (f16)(-im);
        }
        *(float4*)(U + (size_t)l * 64 + c0) = *(const float4*)vals;
    }
}

// ---------------------------------------------------------------------------
// CM1 (MFMA): h = prelu(linear_w @ x + b), fp32 in -> f16 out.
// ---------------------------------------------------------------------------
__global__ __launch_bounds__(256) void k_cm1m(const float* __restrict__ x,
                                              const float* __restrict__ W,
                                              const float* __restrict__ bias,
                                              f16* __restrict__ dst,
                                              const float* __restrict__ aptr) {
    int t = threadIdx.x, bi = blockIdx.x;
    int b = bi >> 6;
    int wv = t >> 6, lane = t & 63;
    int qd = lane >> 4, ln = lane & 15;
    int colw = ((bi & 63) << 8) + wv * 64;
    const float* xb = x + (size_t)b * HH * LL;
    f32x4 acc[4][4];
#pragma unroll
    for (int a = 0; a < 4; a++)
#pragma unroll
        for (int nb = 0; nb < 4; nb++) acc[a][nb] = (f32x4)0.0f;
#pragma unroll
    for (int ks = 0; ks < 2; ks++) {
        f16x8 whi[4], wlo[4];
#pragma unroll
        for (int a = 0; a < 4; a++) {
            const float* wp = W + (size_t)(a * 16 + ln) * 64 + ks * 32 + qd * 8;
#pragma unroll
            for (int j = 0; j < 8; j++) {
                float f = wp[j];
                f16 hv = (f16)f;
                whi[a][j] = hv;
                wlo[a][j] = (f16)(f - (float)hv);
            }
        }
        f16x8 bhi[4], blo[4];
#pragma unroll
        for (int nb = 0; nb < 4; nb++) {
            const float* xp = xb + (size_t)(ks * 32 + qd * 8) * LL + colw + nb * 16 + ln;
#pragma unroll
            for (int j = 0; j < 8; j++) {
                float f = xp[(size_t)j * LL];
                f16 hv = (f16)f;
                bhi[nb][j] = hv;
                blo[nb][j] = (f16)(f - (float)hv);
            }
        }
#pragma unroll
        for (int a = 0; a < 4; a++)
#pragma unroll
            for (int nb = 0; nb < 4; nb++)
                acc[a][nb] = __builtin_amdgcn_mfma_f32_16x16x32_f16(whi[a], bhi[nb], acc[a][nb], 0, 0, 0);
#pragma unroll
        for (int a = 0; a < 4; a++)
#pragma unroll
            for (int nb = 0; nb < 4; nb++)
                acc[a][nb] = __builtin_amdgcn_mfma_f32_16x16x32_f16(whi[a], blo[nb], acc[a][nb], 0, 0, 0);
#pragma unroll
        for (int a = 0; a < 4; a++)
#pragma unroll
            for (int nb = 0; nb < 4; nb++)
                acc[a][nb] = __builtin_amdgcn_mfma_f32_16x16x32_f16(wlo[a], bhi[nb], acc[a][nb], 0, 0, 0);
    }
    float a1 = *aptr;
    f16* dp = dst + (size_t)b * HH * LL;
#pragma unroll
    for (int a = 0; a < 4; a++)
#pragma unroll
        for (int r = 0; r < 4; r++) {
            int g = a * 16 + qd * 4 + r;
            float bb = bias[g];
            f16* gp = dp + (size_t)g * LL + colw + ln;
#pragma unroll
            for (int nb = 0; nb < 4; nb++) {
                float v = acc[a][nb][r] + bb;
                v = (v >= 0.0f) ? v : a1 * v;
                gp[nb * 16] = (f16)v;
            }
        }
}

// ---------------------------------------------------------------------------
// CM2-STATS (MFMA): computes y2 = out_w @ y1 + out_b in registers, reduces
// BN sum/sumsq per channel, writes ONLY per-block partials to the dead P
// region. y2 is never stored (k6m recomputes it bit-identically).
// ---------------------------------------------------------------------------
__global__ __launch_bounds__(256) void k_cm2s(const f16* __restrict__ y1,
                                              const float* __restrict__ W,
                                              const float* __restrict__ bias,
                                              float* __restrict__ ws) {
    __shared__ float bns[64], bnss[64];
    int t = threadIdx.x, bi = blockIdx.x;
    int b = bi >> 6;
    int wv = t >> 6, lane = t & 63;
    int qd = lane >> 4, ln = lane & 15;
    int colw = ((bi & 63) << 8) + wv * 64;
    const f16* yb = y1 + (size_t)b * HH * LL;
    if (t < 64) { bns[t] = 0.0f; bnss[t] = 0.0f; }
    __syncthreads();
    f32x4 acc[4][4];
#pragma unroll
    for (int a = 0; a < 4; a++)
#pragma unroll
        for (int nb = 0; nb < 4; nb++) acc[a][nb] = (f32x4)0.0f;
#pragma unroll
    for (int ks = 0; ks < 2; ks++) {
        f16x8 whi[4], wlo[4];
#pragma unroll
        for (int a = 0; a < 4; a++) {
            const float* wp = W + (size_t)(a * 16 + ln) * 64 + ks * 32 + qd * 8;
#pragma unroll
            for (int j = 0; j < 8; j++) {
                float f = wp[j];
                f16 hv = (f16)f;
                whi[a][j] = hv;
                wlo[a][j] = (f16)(f - (float)hv);
            }
        }
        f16x8 bf[4];
#pragma unroll
        for (int nb = 0; nb < 4; nb++) {
            const f16* yp = yb + (size_t)(ks * 32 + qd * 8) * LL + colw + nb * 16 + ln;
#pragma unroll
            for (int j = 0; j < 8; j++)
                bf[nb][j] = yp[(size_t)j * LL];
        }
#pragma unroll
        for (int a = 0; a < 4; a++)
#pragma unroll
            for (int nb = 0; nb < 4; nb++)
                acc[a][nb] = __builtin_amdgcn_mfma_f32_16x16x32_f16(whi[a], bf[nb], acc[a][nb], 0, 0, 0);
#pragma unroll
        for (int a = 0; a < 4; a++)
#pragma unroll
            for (int nb = 0; nb < 4; nb++)
                acc[a][nb] = __builtin_amdgcn_mfma_f32_16x16x32_f16(wlo[a], bf[nb], acc[a][nb], 0, 0, 0);
    }
#pragma unroll
    for (int a = 0; a < 4; a++)
#pragma unroll
        for (int r = 0; r < 4; r++) {
            int g = a * 16 + qd * 4 + r;
            float bb = bias[g];
            float s = 0.0f, ssq = 0.0f;
#pragma unroll
            for (int nb = 0; nb < 4; nb++) {
                float v = acc[a][nb][r] + bb;
                s += v; ssq += v * v;
            }
#pragma unroll
            for (int off = 1; off < 16; off <<= 1) {
                s += __shfl_xor(s, off);
                ssq += __shfl_xor(ssq, off);
            }
            if (ln == 0) {
                atomicAdd(&bns[g], s);
                atomicAdd(&bnss[g], ssq);
            }
        }
    __syncthreads();
    if (t < 64) {
        float* part = ws + OFF_P;
        part[(size_t)bi * 128 + t] = bns[t];
        part[(size_t)bi * 128 + 64 + t] = bnss[t];
    }
}

// ---------------------------------------------------------------------------
// GEMM A: P(64x1024) = V(64x256) @ H(256x1024) per channel, fp32 out.
// ---------------------------------------------------------------------------
__global__ __launch_bounds__(256) void gemmA(float* __restrict__ ws) {
    __shared__ __align__(16) char smem[25600];
    f16* Vs = (f16*)smem;                 // [64][stride 40]
    f16* Hs = (f16*)(smem + 5120);        // [256][stride 40]
    int t = threadIdx.x;
    int bid = blockIdx.x;
    int ch = bid & 63, ntile = bid >> 6;
    const f16* Vm = (const f16*)(ws + OFF_V) + (size_t)ch * 16384;
    const f16* H  = (const f16*)(ws + OFF_H);
    int w = t >> 6, lane = t & 63;
    int qd = lane >> 4, ln = lane & 15;
    f32x4 acc[4][4];
#pragma unroll
    for (int a = 0; a < 4; a++)
#pragma unroll
        for (int nb = 0; nb < 4; nb++) acc[a][nb] = (f32x4)0.0f;
    int colg = ntile * 256 + t;
    const f16* hcol = H + ((size_t)(colg >> 6) * 64 + ch) * 16384 + (size_t)(colg & 63) * 256;
    int vrow = t >> 2, vkg = t & 3;
    for (int k0 = 0; k0 < 256; k0 += 32) {
        __syncthreads();
        *(float4*)&Vs[vrow * 40 + vkg * 8] = *(const float4*)(Vm + vrow * 256 + k0 + vkg * 8);
#pragma unroll
        for (int kg = 0; kg < 4; kg++)
            *(float4*)&Hs[t * 40 + kg * 8] = *(const float4*)(hcol + k0 + kg * 8);
        __syncthreads();
        f16x8 af[4], bf[4];
#pragma unroll
        for (int a = 0; a < 4; a++) af[a] = *(f16x8*)&Vs[(a * 16 + ln) * 40 + qd * 8];
#pragma unroll
        for (int nb = 0; nb < 4; nb++) bf[nb] = *(f16x8*)&Hs[(w * 64 + nb * 16 + ln) * 40 + qd * 8];
#pragma unroll
        for (int a = 0; a < 4; a++)
#pragma unroll
            for (int nb = 0; nb < 4; nb++)
                acc[a][nb] = __builtin_amdgcn_mfma_f32_16x16x32_f16(af[a], bf[nb], acc[a][nb], 0, 0, 0);
    }
    float* P = ws + OFF_P;
#pragma unroll
    for (int a = 0; a < 4; a++)
#pragma unroll
        for (int nb = 0; nb < 4; nb++)
#pragma unroll
            for (int r = 0; r < 4; r++) {
                int row = a * 16 + qd * 4 + r;
                int col = ntile * 256 + w * 64 + nb * 16 + ln;
                P[((size_t)ch * 64 + row) * 1024 + col] = acc[a][nb][r];
            }
}

// ---------------------------------------------------------------------------
// K3: sequential carry scan over chunks; writes S_in per chunk as f16 (S_t).
// ---------------------------------------------------------------------------
__global__ __launch_bounds__(256) void k3_scan(float* __restrict__ ws) {
    int tid = blockIdx.x * 256 + threadIdx.x;  // 0..32767
    int ch = tid >> 9, b = (tid >> 5) & 15, n = tid & 31;
    const float* P = ws + OFF_P;
    f16* S = (f16*)(ws + OFF_S);
    float2 wl = ((const float2*)(ws + OFF_WL))[ch * 32 + n];
    float sr = 0.0f, si = 0.0f;
    const float* pre = P + ((size_t)ch * 64 + n) * 1024 + b * 64;
    const float* pim = P + ((size_t)ch * 64 + 32 + n) * 1024 + b * 64;
    f16* srow = S + ((size_t)ch * 1024 + b * 64) * 64 + 2 * n;
    for (int c = 0; c < 64; c++) {
        srow[c * 64]     = (f16)sr;
        srow[c * 64 + 1] = (f16)si;
        float pr = pre[c], pi = pim[c];
        float nr = fmaf(wl.x, sr, fmaf(-wl.y, si, pr));
        float ni = fmaf(wl.y, sr, fmaf(wl.x, si, pi));
        sr = nr; si = ni;
    }
}

// ---------------------------------------------------------------------------
// GEMM MAIN v4 (LDS-staged + stage-skip + T14 async-STAGE split):
// per channel: Y1(256x1024) = T'(256x256)@H + U(256x64)@S.
// grid 1024: ch = bid&63 (XCD-colocated), ntile = bid>>6 (64 cols each).
// Round k's staging data is loaded into REGISTERS during round k-1's
// compute (issued right after the second barrier), so the global-load
// latency hides under MFMA instead of sitting on the ds_write critical
// path. Prefetch guard t >= (k0+32)-16 matches the next round's write
// guard. The last T round prefetches U/S. Same arithmetic as r8.
// y1 f16 written IN PLACE over H.
// ---------------------------------------------------------------------------
__global__ __launch_bounds__(256) void gemmMain(float* __restrict__ ws) {
    __shared__ __align__(16) char smem[25600];
    f16* Ts = (f16*)smem;                  // [256][stride 40] (also Us)
    f16* Hs = (f16*)(smem + 20480);        // [64][stride 40]  (also Ss)
    f16* Ys = (f16*)smem;                  // [64][stride 136]
    int t = threadIdx.x;
    int bid = blockIdx.x;
    int ch = bid & 63, ntile = bid >> 6;
    const f16* Tm = (const f16*)(ws + OFF_T) + (size_t)ch * 65536;
    const f16* Um = (const f16*)(ws + OFF_U) + (size_t)ch * 16384;
    const f16* H  = (const f16*)(ws + OFF_H);
    const f16* St = (const f16*)(ws + OFF_S);
    f16* y1 = (f16*)(ws + OFF_H);          // in-place over H
    int w = t >> 6, lane = t & 63;
    int qd = lane >> 4, ln = lane & 15;
    f32x4 acc[4][4];
#pragma unroll
    for (int a = 0; a < 4; a++)
#pragma unroll
        for (int nb = 0; nb < 4; nb++) acc[a][nb] = (f32x4)0.0f;
    int scol = t >> 2, skg = t & 3;        // staging role for Hs/Ss
    int colg = ntile * 64 + scol;
    const f16* hcol = H + ((size_t)(colg >> 6) * 64 + ch) * 16384 + (size_t)(colg & 63) * 256;
    const f16* sscol = St + ((size_t)ch * 1024 + colg) * 64;
    // prefetch registers (T14 async-STAGE split)
    float4 tr[4];
    float4 hr;
    // prologue: load round k0=0
#pragma unroll
    for (int kg = 0; kg < 4; kg++)
        tr[kg] = *(const float4*)(Tm + (size_t)t * 256 + kg * 8);
    hr = *(const float4*)(hcol + skg * 8);
    // ---- T @ H ----
    for (int k0 = 0; k0 < 256; k0 += 32) {
        __syncthreads();
        if (t >= k0 - 16) {                 // rows < k0-16 are never consumed
#pragma unroll
            for (int kg = 0; kg < 4; kg++)
                *(float4*)&Ts[t * 40 + kg * 8] = tr[kg];
        }
        *(float4*)&Hs[scol * 40 + skg * 8] = hr;
        __syncthreads();
        // issue next round's loads BEFORE compute (latency hides under MFMA)
        if (k0 < 224) {
            int kn = k0 + 32;
            if (t >= kn - 16) {
#pragma unroll
                for (int kg = 0; kg < 4; kg++)
                    tr[kg] = *(const float4*)(Tm + (size_t)t * 256 + kn + kg * 8);
            }
            hr = *(const float4*)(hcol + kn + skg * 8);
        } else {
            // prefetch first U/S round
#pragma unroll
            for (int kg = 0; kg < 4; kg++)
                tr[kg] = *(const float4*)(Um + (size_t)t * 64 + kg * 8);
            hr = *(const float4*)(sscol + skg * 8);
        }
        if (k0 <= w * 64 + 63) {
            f16x8 bf[4];
#pragma unroll
            for (int nb = 0; nb < 4; nb++) bf[nb] = *(f16x8*)&Hs[(nb * 16 + ln) * 40 + qd * 8];
#pragma unroll
            for (int a = 0; a < 4; a++) {
                if (k0 <= w * 64 + a * 16 + 15) {
                    f16x8 af = *(f16x8*)&Ts[(w * 64 + a * 16 + ln) * 40 + qd * 8];
#pragma unroll
                    for (int nb = 0; nb < 4; nb++)
                        acc[a][nb] = __builtin_amdgcn_mfma_f32_16x16x32_f16(af, bf[nb], acc[a][nb], 0, 0, 0);
                }
            }
        }
    }
    // ---- U @ S ----
    for (int k0 = 0; k0 < 64; k0 += 32) {
        __syncthreads();
#pragma unroll
        for (int kg = 0; kg < 4; kg++)
            *(float4*)&Ts[t * 40 + kg * 8] = tr[kg];
        *(float4*)&Hs[scol * 40 + skg * 8] = hr;
        __syncthreads();
        if (k0 == 0) {
#pragma unroll
            for (int kg = 0; kg < 4; kg++)
                tr[kg] = *(const float4*)(Um + (size_t)t * 64 + 32 + kg * 8);
            hr = *(const float4*)(sscol + 32 + skg * 8);
        }
        f16x8 bf[4];
#pragma unroll
        for (int nb = 0; nb < 4; nb++) bf[nb] = *(f16x8*)&Hs[(nb * 16 + ln) * 40 + qd * 8];
#pragma unroll
        for (int a = 0; a < 4; a++) {
            f16x8 af = *(f16x8*)&Ts[(w * 64 + a * 16 + ln) * 40 + qd * 8];
#pragma unroll
            for (int nb = 0; nb < 4; nb++)
                acc[a][nb] = __builtin_amdgcn_mfma_f32_16x16x32_f16(af, bf[nb], acc[a][nb], 0, 0, 0);
        }
    }
    // ---- epilogue: transpose through LDS, write y1 f16 [b][ch][l] in place ----
    int ocol = t >> 2, ojg = t & 3;
    int ocolg = ntile * 64 + ocol;
    f16* ybase = y1 + ((size_t)(ocolg >> 6) * 64 + ch) * 16384 + (size_t)(ocolg & 63) * 256;
    for (int hf = 0; hf < 2; hf++) {
        __syncthreads();
        if ((w >> 1) == hf) {
            int jl0 = (w & 1) * 64;
#pragma unroll
            for (int a = 0; a < 4; a++)
#pragma unroll
                for (int nb = 0; nb < 4; nb++)
#pragma unroll
                    for (int r = 0; r < 4; r++)
                        Ys[(nb * 16 + ln) * 136 + jl0 + a * 16 + qd * 4 + r] = (f16)acc[a][nb][r];
        }
        __syncthreads();
#pragma unroll
        for (int i = 0; i < 4; i++)
            *(float4*)(ybase + hf * 128 + ojg * 32 + i * 8) =
                *(const float4*)&Ys[ocol * 136 + ojg * 32 + i * 8];
    }
}

// ---------------------------------------------------------------------------
// K5c: reduce 1024 per-block BN partials -> mean, 1/sqrt(var+eps) per channel.
// grid 64 (one block per channel).
// ---------------------------------------------------------------------------
__global__ __launch_bounds__(256) void k5c_bnfin(float* __restrict__ ws) {
    int ch = blockIdx.x;
    int t = threadIdx.x;
    const float* part = ws + OFF_P;
    float s = 0.0f, ss = 0.0f;
#pragma unroll
    for (int i = 0; i < 4; i++) {
        int pb = t + i * 256;
        s  += part[(size_t)pb * 128 + ch];
        ss += part[(size_t)pb * 128 + 64 + ch];
    }
    for (int off = 32; off; off >>= 1) {
        s += __shfl_xor(s, off);
        ss += __shfl_xor(ss, off);
    }
    __shared__ float as_[4], ass_[4];
    int wv = t >> 6;
    if ((t & 63) == 0) { as_[wv] = s; ass_[wv] = ss; }
    __syncthreads();
    if (t == 0) {
        float S = as_[0] + as_[1] + as_[2] + as_[3];
        float SS = ass_[0] + ass_[1] + ass_[2] + ass_[3];
        float cnt = (float)BL;
        float mean = S / cnt;
        float var = SS / cnt - mean * mean;
        ws[OFF_BNF + ch] = mean;
        ws[OFF_BNF + 64 + ch] = 1.0f / sqrtf(var + 1e-5f);
    }
}

// ---------------------------------------------------------------------------
// K6M (MFMA-fused final): recomputes y2 = out_w @ y1 + out_b with the
// bit-identical MFMA sequence as k_cm2s, then applies BN + FiLM + PReLU +
// depthwise residual in registers and writes out directly.
// ---------------------------------------------------------------------------
__global__ __launch_bounds__(256) void k6m(const f16* __restrict__ y1,
                                           const float* __restrict__ W,
                                           const float* __restrict__ bias,
                                           const float* __restrict__ x,
                                           const float* __restrict__ ws,
                                           const float* __restrict__ a2p,
                                           const float* __restrict__ res_w,
                                           float* __restrict__ out) {
    int t = threadIdx.x, bi = blockIdx.x;
    int b = bi >> 6;
    int wv = t >> 6, lane = t & 63;
    int qd = lane >> 4, ln = lane & 15;
    int colw = ((bi & 63) << 8) + wv * 64;
    const f16* yb = y1 + (size_t)b * HH * LL;
    f32x4 acc[4][4];
#pragma unroll
    for (int a = 0; a < 4; a++)
#pragma unroll
        for (int nb = 0; nb < 4; nb++) acc[a][nb] = (f32x4)0.0f;
#pragma unroll
    for (int ks = 0; ks < 2; ks++) {
        f16x8 whi[4], wlo[4];
#pragma unroll
        for (int a = 0; a < 4; a++) {
            const float* wp = W + (size_t)(a * 16 + ln) * 64 + ks * 32 + qd * 8;
#pragma unroll
            for (int j = 0; j < 8; j++) {
                float f = wp[j];
                f16 hv = (f16)f;
                whi[a][j] = hv;
                wlo[a][j] = (f16)(f - (float)hv);
            }
        }
        f16x8 bf[4];
#pragma unroll
        for (int nb = 0; nb < 4; nb++) {
            const f16* yp = yb + (size_t)(ks * 32 + qd * 8) * LL + colw + nb * 16 + ln;
#pragma unroll
            for (int j = 0; j < 8; j++)
                bf[nb][j] = yp[(size_t)j * LL];
        }
#pragma unroll
        for (int a = 0; a < 4; a++)
#pragma unroll
            for (int nb = 0; nb < 4; nb++)
                acc[a][nb] = __builtin_amdgcn_mfma_f32_16x16x32_f16(whi[a], bf[nb], acc[a][nb], 0, 0, 0);
#pragma unroll
        for (int a = 0; a < 4; a++)
#pragma unroll
            for (int nb = 0; nb < 4; nb++)
                acc[a][nb] = __builtin_amdgcn_mfma_f32_16x16x32_f16(wlo[a], bf[nb], acc[a][nb], 0, 0, 0);
    }
    float a2 = *a2p;
    const float* xb = x + (size_t)b * HH * LL;
    float* ob = out + (size_t)b * HH * LL;
#pragma unroll
    for (int a = 0; a < 4; a++)
#pragma unroll
        for (int r = 0; r < 4; r++) {
            int g = a * 16 + qd * 4 + r;
            float bb = bias[g];
            float gamma = ws[OFF_GB + b * 128 + g];
            float beta  = ws[OFF_GB + b * 128 + 64 + g];
            float mean = ws[OFF_BNF + g];
            float inv  = ws[OFF_BNF + 64 + g];
            float scale = gamma * inv;
            float shift = beta - scale * mean;
            float rw = res_w[g];
            const float* xp = xb + (size_t)g * LL + colw + ln;
            float* op = ob + (size_t)g * LL + colw + ln;
#pragma unroll
            for (int nb = 0; nb < 4; nb++) {
                float v = acc[a][nb][r] + bb;       // y2 (bit-identical to cm2s)
                v = fmaf(scale, v, shift);
                v = (v >= 0.0f) ? v : a2 * v;
                op[nb * 16] = fmaf(rw, xp[nb * 16], v);
            }
        }
}

// ---------------------------------------------------------------------------
extern "C" void kernel_launch(void* const* d_in, const int* in_sizes, int n_in,
                              void* d_out, int out_size, void* d_ws, size_t ws_size,
                              hipStream_t stream) {
    const float* x        = (const float*)d_in[0];
    const float* cond     = (const float*)d_in[1];
    const float* linear_w = (const float*)d_in[2];
    const float* linear_b = (const float*)d_in[3];
    const float* prelu1_a = (const float*)d_in[4];
    const float* log_dt   = (const float*)d_in[5];
    const float* log_A    = (const float*)d_in[6];
    const float* A_imag   = (const float*)d_in[7];
    const float* C_re     = (const float*)d_in[8];
    const float* C_im     = (const float*)d_in[9];
    const float* Dskip    = (const float*)d_in[10];
    const float* out_w    = (const float*)d_in[11];
    const float* out_b    = (const float*)d_in[12];
    const float* film_w   = (const float*)d_in[13];
    const float* film_b   = (const float*)d_in[14];
    const float* prelu2_a = (const float*)d_in[15];
    const float* res_w    = (const float*)d_in[16];
    float* ws  = (float*)d_ws;
    float* out = (float*)d_out;
    f16* hbuf = (f16*)(ws + OFF_H);
    f16* y1   = (f16*)(ws + OFF_H);   // y1 aliases h (overwritten in place)

    hipLaunchKernelGGL(k0_setup, dim3(16), dim3(256), 0, stream,
                       log_dt, log_A, A_imag, C_re, C_im, cond, film_w, film_b, ws);
    hipLaunchKernelGGL(kprep, dim3(64), dim3(256), 0, stream,
                       log_dt, log_A, A_imag, Dskip, ws);
    hipLaunchKernelGGL(kbuild, dim3(1024), dim3(256), 0, stream,
                       log_dt, log_A, A_imag, ws);
    hipLaunchKernelGGL(k_cm1m, dim3(1024), dim3(256), 0, stream,
                       x, linear_w, linear_b, hbuf, prelu1_a);
    hipLaunchKernelGGL(gemmA, dim3(256), dim3(256), 0, stream, ws);
    hipLaunchKernelGGL(k3_scan, dim3(128), dim3(256), 0, stream, ws);
    hipLaunchKernelGGL(gemmMain, dim3(1024), dim3(256), 0, stream, ws);
    hipLaunchKernelGGL(k_cm2s, dim3(1024), dim3(256), 0, stream,
                       y1, out_w, out_b, ws);
    hipLaunchKernelGGL(k5c_bnfin, dim3(64), dim3(256), 0, stream, ws);
    hipLaunchKernelGGL(k6m, dim3(1024), dim3(256), 0, stream,
                       y1, out_w, out_b, x, ws, prelu2_a, res_w, out);
}

// Round 12
// 274.166 us; speedup vs baseline: 1.1154x; 1.1154x over previous
//
#include <hip/hip_runtime.h>
#include <math.h>

// Problem constants
#define BB 16
#define HH 64
#define LL 16384
#define NST 32
#define LC 256
#define CC 64              // LL/LC
#define BL (BB*LL)         // 262144

typedef _Float16 f16;
typedef f16  f16x8 __attribute__((ext_vector_type(8)));
typedef float f32x4 __attribute__((ext_vector_type(4)));

// ws layout (float offsets). Total ~71.4 MB.
// NOTE: y1 is written IN PLACE over OFF_H by gemmMain (each (ch,col) owned by
// exactly one block; gemmA, the only other H reader, runs before it).
// NOTE: OFF_P is reused three times: m0_setup (kprep part) writes Kl[64][256],
// gemmA overwrites all of P, k_cm2s reuses it for BN partials.
// NOTE: y2 is NEVER materialized — k_cm2s computes stats from registers;
// k6m recomputes the bit-identical y2 and applies BN/FiLM/PReLU/residual.
#define OFF_H   ((size_t)0)            // h f16 -> later y1 f16: 16,777,216 halves
#define OFF_P   ((size_t)8388608)      // P fp32: 64ch x 64row x 1024col; Kl; BN partials
#define OFF_S   ((size_t)12582912)     // S_t f16: [ch][1024 col][64 row]
#define OFF_T   ((size_t)14680064)     // T f16: [ch][256][256]
#define OFF_V   ((size_t)16777216)     // V f16: [ch][64][256]
#define OFF_U   ((size_t)17301504)     // U f16: [ch][256][64]
#define OFF_PW  ((size_t)17825792)     // per-state params float4 x 2048
#define OFF_WL  ((size_t)17833984)     // w^Lc: float2 x 2048
#define OFF_GB  ((size_t)17838080)     // FiLM gamma/beta: 2048
#define OFF_BN  ((size_t)17840128)     // (unused now)
#define OFF_BNF ((size_t)17840256)     // BN mean/inv: 128

// ---------------------------------------------------------------------------
// M0: merged setup. grid 80:
//  bid 0-7  : PW (w, 2*Cd) + WL (w^Lc), one state per thread
//  bid 8-15 : FiLM gamma/beta, one output per thread
//  bid 16-79: kprep for ch=bid-16 -> Kl[ch][d] into the dead P region.
//             (recomputes c2r/c2i with the BIT-IDENTICAL op sequence the
//              bid<8 branch uses, so no inter-kernel dependency is needed)
// ---------------------------------------------------------------------------
__global__ __launch_bounds__(256) void m0_setup(const float* __restrict__ log_dt,
                         const float* __restrict__ log_A_real,
                         const float* __restrict__ A_imag,
                         const float* __restrict__ C_re,
                         const float* __restrict__ C_im,
                         const float* __restrict__ cond,
                         const float* __restrict__ film_w,
                         const float* __restrict__ film_b,
                         const float* __restrict__ Dskip,
                         float* __restrict__ ws) {
    int t = threadIdx.x, bid = blockIdx.x;
    if (bid < 8) {
        float4* pw = (float4*)(ws + OFF_PW);
        float2* wl = (float2*)(ws + OFF_WL);
        int idx = bid * 256 + t;             // state index = ch*32 + n
        int ch = idx >> 5;
        float dt  = expf(log_dt[ch]);
        float are = -expf(log_A_real[idx]);
        float aim = A_imag[idx];
        float dr = are * dt, di = aim * dt;
        float er = expf(dr);
        float wr = er * cosf(di);
        float wi = er * sinf(di);
        float inv = 1.0f / (are * are + aim * aim);
        float gr = ((wr - 1.0f) * are + wi * aim) * inv;
        float gi = (wi * are - (wr - 1.0f) * aim) * inv;
        float cr = C_re[idx], ci = C_im[idx];
        float cdr = cr * gr - ci * gi;
        float cdi = cr * gi + ci * gr;
        pw[idx] = make_float4(wr, wi, 2.0f * cdr, 2.0f * cdi);
        float erL = expf(dr * (float)LC);
        wl[idx] = make_float2(erL * cosf(di * (float)LC), erL * sinf(di * (float)LC));
    } else if (bid < 16) {
        float* gb = ws + OFF_GB;
        int o = (bid - 8) * 256 + t;         // o = b*128 + j
        int b = o >> 7, j = o & 127;
        float acc = film_b[j];
        for (int q = 0; q < 128; q++)
            acc = fmaf(cond[b * 128 + q], film_w[j * 128 + q], acc);
        gb[o] = acc;
    } else {
        // kprep: Kl[ch][d] = sum_n Re(2Cd_n w_n^d) (+Dskip at d==0)
        __shared__ float drs[32], dis[32], c2r[32], c2i[32];
        int ch = bid - 16;
        if (t < 32) {
            float dt = expf(log_dt[ch]);
            float are = -expf(log_A_real[ch * 32 + t]);
            float aim = A_imag[ch * 32 + t];
            float dr = are * dt, di = aim * dt;
            float er = expf(dr);
            float wr = er * cosf(di);
            float wi = er * sinf(di);
            float inv = 1.0f / (are * are + aim * aim);
            float gr = ((wr - 1.0f) * are + wi * aim) * inv;
            float gi = (wi * are - (wr - 1.0f) * aim) * inv;
            float cr = C_re[ch * 32 + t], ci = C_im[ch * 32 + t];
            float cdr = cr * gr - ci * gi;
            float cdi = cr * gi + ci * gr;
            drs[t] = dr; dis[t] = di;
            c2r[t] = 2.0f * cdr; c2i[t] = 2.0f * cdi;
        }
        __syncthreads();
        float acc = 0.0f;
        float fd = (float)t;
        for (int n = 0; n < 32; n++) {
            float e = expf(drs[n] * fd);
            float ph = dis[n] * fd;
            acc += c2r[n] * e * cosf(ph) - c2i[n] * e * sinf(ph);
        }
        if (t == 0) acc += Dskip[ch];
        ws[OFF_P + (size_t)ch * 256 + t] = acc;
    }
}

// ---------------------------------------------------------------------------
// M1: merged kbuild + cm1. grid 2048:
//  bid < 1024 : kbuild part (64 ch x 16 parts) — T/V/U f16 matrices from Kl
//  bid >= 1024: cm1 part — h = prelu(linear_w @ x + b) via MFMA, f16 out
// The two halves touch disjoint memory; merging overlaps kbuild under cm1.
// ---------------------------------------------------------------------------
__global__ __launch_bounds__(256) void m1_build_cm1(const float* __restrict__ log_dt,
                                              const float* __restrict__ log_A,
                                              const float* __restrict__ A_imag,
                                              const float* __restrict__ x,
                                              const float* __restrict__ W,
                                              const float* __restrict__ bias,
                                              const float* __restrict__ aptr,
                                              float* __restrict__ ws) {
    __shared__ float Kl[256];
    __shared__ float drs[32], dis[32], c2r[32], c2i[32];
    int t = threadIdx.x, bid0 = blockIdx.x;
    if (bid0 < 1024) {
        int bid = bid0;
        int ch = bid >> 4, part = bid & 15;
        if (t < 32) {
            float dt = expf(log_dt[ch]);
            float are = -expf(log_A[ch * 32 + t]);
            float aim = A_imag[ch * 32 + t];
            drs[t] = are * dt; dis[t] = aim * dt;
            float4 p = ((const float4*)(ws + OFF_PW))[ch * 32 + t];
            c2r[t] = p.z; c2i[t] = p.w;
        }
        Kl[t] = ws[OFF_P + (size_t)ch * 256 + t];
        __syncthreads();
        f16* T = (f16*)(ws + OFF_T) + (size_t)ch * 65536;
        {
            int r0 = part * 16;
#pragma unroll
            for (int i = 0; i < 2; i++) {
                int idx = t + i * 256;
                int row = r0 + (idx >> 5);
                int c0 = (idx & 31) * 8;
                f16 vals[8];
#pragma unroll
                for (int j = 0; j < 8; j++) {
                    int c = c0 + j;
                    vals[j] = (f16)((c <= row) ? Kl[row - c] : 0.0f);
                }
                *(float4*)(T + (size_t)row * 256 + c0) = *(const float4*)vals;
            }
        }
        if (part < 8) {
            f16* V = (f16*)(ws + OFF_V) + (size_t)ch * 16384;
            int row = part * 8 + (t >> 5);
            int c0 = (t & 31) * 8;
            int n = row & 31;
            f16 vals[8];
#pragma unroll
            for (int j = 0; j < 8; j++) {
                float fe = (float)(255 - (c0 + j));
                float e = expf(drs[n] * fe);
                float ph = dis[n] * fe;
                vals[j] = (f16)((row < 32) ? e * cosf(ph) : e * sinf(ph));
            }
            *(float4*)(V + (size_t)row * 256 + c0) = *(const float4*)vals;
        } else {
            f16* U = (f16*)(ws + OFF_U) + (size_t)ch * 16384;
            int l = (part - 8) * 32 + (t >> 3);
            int c0 = (t & 7) * 8;
            float fl1 = (float)(l + 1);
            f16 vals[8];
#pragma unroll
            for (int nn = 0; nn < 4; nn++) {
                int n = (c0 >> 1) + nn;
                float e = expf(drs[n] * fl1);
                float ph = dis[n] * fl1;
                float wre = e * cosf(ph), wim = e * sinf(ph);
                float re = c2r[n] * wre - c2i[n] * wim;
                float im = c2r[n] * wim + c2i[n] * wre;
                vals[2 * nn]     = (f16)re;
                vals[2 * nn + 1] = (f16)(-im);
            }
            *(float4*)(U + (size_t)l * 64 + c0) = *(const float4*)vals;
        }
    } else {
        // ---- cm1 part ----
        int bi = bid0 - 1024;
        f16* dst = (f16*)(ws + OFF_H);
        int b = bi >> 6;
        int wv = t >> 6, lane = t & 63;
        int qd = lane >> 4, ln = lane & 15;
        int colw = ((bi & 63) << 8) + wv * 64;
        const float* xb = x + (size_t)b * HH * LL;
        f32x4 acc[4][4];
#pragma unroll
        for (int a = 0; a < 4; a++)
#pragma unroll
            for (int nb = 0; nb < 4; nb++) acc[a][nb] = (f32x4)0.0f;
#pragma unroll
        for (int ks = 0; ks < 2; ks++) {
            f16x8 whi[4], wlo[4];
#pragma unroll
            for (int a = 0; a < 4; a++) {
                const float* wp = W + (size_t)(a * 16 + ln) * 64 + ks * 32 + qd * 8;
#pragma unroll
                for (int j = 0; j < 8; j++) {
                    float f = wp[j];
                    f16 hv = (f16)f;
                    whi[a][j] = hv;
                    wlo[a][j] = (f16)(f - (float)hv);
                }
            }
            f16x8 bhi[4], blo[4];
#pragma unroll
            for (int nb = 0; nb < 4; nb++) {
                const float* xp = xb + (size_t)(ks * 32 + qd * 8) * LL + colw + nb * 16 + ln;
#pragma unroll
                for (int j = 0; j < 8; j++) {
                    float f = xp[(size_t)j * LL];
                    f16 hv = (f16)f;
                    bhi[nb][j] = hv;
                    blo[nb][j] = (f16)(f - (float)hv);
                }
            }
#pragma unroll
            for (int a = 0; a < 4; a++)
#pragma unroll
                for (int nb = 0; nb < 4; nb++)
                    acc[a][nb] = __builtin_amdgcn_mfma_f32_16x16x32_f16(whi[a], bhi[nb], acc[a][nb], 0, 0, 0);
#pragma unroll
            for (int a = 0; a < 4; a++)
#pragma unroll
                for (int nb = 0; nb < 4; nb++)
                    acc[a][nb] = __builtin_amdgcn_mfma_f32_16x16x32_f16(whi[a], blo[nb], acc[a][nb], 0, 0, 0);
#pragma unroll
            for (int a = 0; a < 4; a++)
#pragma unroll
                for (int nb = 0; nb < 4; nb++)
                    acc[a][nb] = __builtin_amdgcn_mfma_f32_16x16x32_f16(wlo[a], bhi[nb], acc[a][nb], 0, 0, 0);
        }
        float a1 = *aptr;
        f16* dp = dst + (size_t)b * HH * LL;
#pragma unroll
        for (int a = 0; a < 4; a++)
#pragma unroll
            for (int r = 0; r < 4; r++) {
                int g = a * 16 + qd * 4 + r;
                float bb = bias[g];
                f16* gp = dp + (size_t)g * LL + colw + ln;
#pragma unroll
                for (int nb = 0; nb < 4; nb++) {
                    float v = acc[a][nb][r] + bb;
                    v = (v >= 0.0f) ? v : a1 * v;
                    gp[nb * 16] = (f16)v;
                }
            }
    }
}

// ---------------------------------------------------------------------------
// CM2-STATS (MFMA): computes y2 = out_w @ y1 + out_b in registers, reduces
// BN sum/sumsq per channel, writes ONLY per-block partials to the dead P
// region. y2 is never stored (k6m recomputes it bit-identically).
// ---------------------------------------------------------------------------
__global__ __launch_bounds__(256) void k_cm2s(const f16* __restrict__ y1,
                                              const float* __restrict__ W,
                                              const float* __restrict__ bias,
                                              float* __restrict__ ws) {
    __shared__ float bns[64], bnss[64];
    int t = threadIdx.x, bi = blockIdx.x;
    int b = bi >> 6;
    int wv = t >> 6, lane = t & 63;
    int qd = lane >> 4, ln = lane & 15;
    int colw = ((bi & 63) << 8) + wv * 64;
    const f16* yb = y1 + (size_t)b * HH * LL;
    if (t < 64) { bns[t] = 0.0f; bnss[t] = 0.0f; }
    __syncthreads();
    f32x4 acc[4][4];
#pragma unroll
    for (int a = 0; a < 4; a++)
#pragma unroll
        for (int nb = 0; nb < 4; nb++) acc[a][nb] = (f32x4)0.0f;
#pragma unroll
    for (int ks = 0; ks < 2; ks++) {
        f16x8 whi[4], wlo[4];
#pragma unroll
        for (int a = 0; a < 4; a++) {
            const float* wp = W + (size_t)(a * 16 + ln) * 64 + ks * 32 + qd * 8;
#pragma unroll
            for (int j = 0; j < 8; j++) {
                float f = wp[j];
                f16 hv = (f16)f;
                whi[a][j] = hv;
                wlo[a][j] = (f16)(f - (float)hv);
            }
        }
        f16x8 bf[4];
#pragma unroll
        for (int nb = 0; nb < 4; nb++) {
            const f16* yp = yb + (size_t)(ks * 32 + qd * 8) * LL + colw + nb * 16 + ln;
#pragma unroll
            for (int j = 0; j < 8; j++)
                bf[nb][j] = yp[(size_t)j * LL];
        }
#pragma unroll
        for (int a = 0; a < 4; a++)
#pragma unroll
            for (int nb = 0; nb < 4; nb++)
                acc[a][nb] = __builtin_amdgcn_mfma_f32_16x16x32_f16(whi[a], bf[nb], acc[a][nb], 0, 0, 0);
#pragma unroll
        for (int a = 0; a < 4; a++)
#pragma unroll
            for (int nb = 0; nb < 4; nb++)
                acc[a][nb] = __builtin_amdgcn_mfma_f32_16x16x32_f16(wlo[a], bf[nb], acc[a][nb], 0, 0, 0);
    }
#pragma unroll
    for (int a = 0; a < 4; a++)
#pragma unroll
        for (int r = 0; r < 4; r++) {
            int g = a * 16 + qd * 4 + r;
            float bb = bias[g];
            float s = 0.0f, ssq = 0.0f;
#pragma unroll
            for (int nb = 0; nb < 4; nb++) {
                float v = acc[a][nb][r] + bb;
                s += v; ssq += v * v;
            }
#pragma unroll
            for (int off = 1; off < 16; off <<= 1) {
                s += __shfl_xor(s, off);
                ssq += __shfl_xor(ssq, off);
            }
            if (ln == 0) {
                atomicAdd(&bns[g], s);
                atomicAdd(&bnss[g], ssq);
            }
        }
    __syncthreads();
    if (t < 64) {
        float* part = ws + OFF_P;
        part[(size_t)bi * 128 + t] = bns[t];
        part[(size_t)bi * 128 + 64 + t] = bnss[t];
    }
}

// ---------------------------------------------------------------------------
// GEMM A: P(64x1024) = V(64x256) @ H(256x1024) per channel, fp32 out.
// ---------------------------------------------------------------------------
__global__ __launch_bounds__(256) void gemmA(float* __restrict__ ws) {
    __shared__ __align__(16) char smem[25600];
    f16* Vs = (f16*)smem;                 // [64][stride 40]
    f16* Hs = (f16*)(smem + 5120);        // [256][stride 40]
    int t = threadIdx.x;
    int bid = blockIdx.x;
    int ch = bid & 63, ntile = bid >> 6;
    const f16* Vm = (const f16*)(ws + OFF_V) + (size_t)ch * 16384;
    const f16* H  = (const f16*)(ws + OFF_H);
    int w = t >> 6, lane = t & 63;
    int qd = lane >> 4, ln = lane & 15;
    f32x4 acc[4][4];
#pragma unroll
    for (int a = 0; a < 4; a++)
#pragma unroll
        for (int nb = 0; nb < 4; nb++) acc[a][nb] = (f32x4)0.0f;
    int colg = ntile * 256 + t;
    const f16* hcol = H + ((size_t)(colg >> 6) * 64 + ch) * 16384 + (size_t)(colg & 63) * 256;
    int vrow = t >> 2, vkg = t & 3;
    for (int k0 = 0; k0 < 256; k0 += 32) {
        __syncthreads();
        *(float4*)&Vs[vrow * 40 + vkg * 8] = *(const float4*)(Vm + vrow * 256 + k0 + vkg * 8);
#pragma unroll
        for (int kg = 0; kg < 4; kg++)
            *(float4*)&Hs[t * 40 + kg * 8] = *(const float4*)(hcol + k0 + kg * 8);
        __syncthreads();
        f16x8 af[4], bf[4];
#pragma unroll
        for (int a = 0; a < 4; a++) af[a] = *(f16x8*)&Vs[(a * 16 + ln) * 40 + qd * 8];
#pragma unroll
        for (int nb = 0; nb < 4; nb++) bf[nb] = *(f16x8*)&Hs[(w * 64 + nb * 16 + ln) * 40 + qd * 8];
#pragma unroll
        for (int a = 0; a < 4; a++)
#pragma unroll
            for (int nb = 0; nb < 4; nb++)
                acc[a][nb] = __builtin_amdgcn_mfma_f32_16x16x32_f16(af[a], bf[nb], acc[a][nb], 0, 0, 0);
    }
    float* P = ws + OFF_P;
#pragma unroll
    for (int a = 0; a < 4; a++)
#pragma unroll
        for (int nb = 0; nb < 4; nb++)
#pragma unroll
            for (int r = 0; r < 4; r++) {
                int row = a * 16 + qd * 4 + r;
                int col = ntile * 256 + w * 64 + nb * 16 + ln;
                P[((size_t)ch * 64 + row) * 1024 + col] = acc[a][nb][r];
            }
}

// ---------------------------------------------------------------------------
// K3: sequential carry scan over chunks; writes S_in per chunk as f16 (S_t).
// ---------------------------------------------------------------------------
__global__ __launch_bounds__(256) void k3_scan(float* __restrict__ ws) {
    int tid = blockIdx.x * 256 + threadIdx.x;  // 0..32767
    int ch = tid >> 9, b = (tid >> 5) & 15, n = tid & 31;
    const float* P = ws + OFF_P;
    f16* S = (f16*)(ws + OFF_S);
    float2 wl = ((const float2*)(ws + OFF_WL))[ch * 32 + n];
    float sr = 0.0f, si = 0.0f;
    const float* pre = P + ((size_t)ch * 64 + n) * 1024 + b * 64;
    const float* pim = P + ((size_t)ch * 64 + 32 + n) * 1024 + b * 64;
    f16* srow = S + ((size_t)ch * 1024 + b * 64) * 64 + 2 * n;
    for (int c = 0; c < 64; c++) {
        srow[c * 64]     = (f16)sr;
        srow[c * 64 + 1] = (f16)si;
        float pr = pre[c], pi = pim[c];
        float nr = fmaf(wl.x, sr, fmaf(-wl.y, si, pr));
        float ni = fmaf(wl.y, sr, fmaf(wl.x, si, pi));
        sr = nr; si = ni;
    }
}

// ---------------------------------------------------------------------------
// GEMM MAIN (LDS-staged + triangular stage-skip — r8 structure, the proven
// 42.3 µs form; reg-prefetch REVERTED, it spilled to scratch +65MB writes):
// per channel: Y1(256x1024) = T'(256x256)@H + U(256x64)@S.
// grid 1024: ch = bid&63 (XCD-colocated), ntile = bid>>6 (64 cols each).
// y1 f16 written IN PLACE over H.
// ---------------------------------------------------------------------------
__global__ __launch_bounds__(256) void gemmMain(float* __restrict__ ws) {
    __shared__ __align__(16) char smem[25600];
    f16* Ts = (f16*)smem;                  // [256][stride 40] (also Us)
    f16* Hs = (f16*)(smem + 20480);        // [64][stride 40]  (also Ss)
    f16* Ys = (f16*)smem;                  // [64][stride 136]
    int t = threadIdx.x;
    int bid = blockIdx.x;
    int ch = bid & 63, ntile = bid >> 6;
    const f16* Tm = (const f16*)(ws + OFF_T) + (size_t)ch * 65536;
    const f16* Um = (const f16*)(ws + OFF_U) + (size_t)ch * 16384;
    const f16* H  = (const f16*)(ws + OFF_H);
    const f16* St = (const f16*)(ws + OFF_S);
    f16* y1 = (f16*)(ws + OFF_H);          // in-place over H
    int w = t >> 6, lane = t & 63;
    int qd = lane >> 4, ln = lane & 15;
    f32x4 acc[4][4];
#pragma unroll
    for (int a = 0; a < 4; a++)
#pragma unroll
        for (int nb = 0; nb < 4; nb++) acc[a][nb] = (f32x4)0.0f;
    int scol = t >> 2, skg = t & 3;        // staging role for Hs/Ss
    int colg = ntile * 64 + scol;
    const f16* hcol = H + ((size_t)(colg >> 6) * 64 + ch) * 16384 + (size_t)(colg & 63) * 256;
    const f16* sscol = St + ((size_t)ch * 1024 + colg) * 64;
    // ---- T @ H ----
    for (int k0 = 0; k0 < 256; k0 += 32) {
        __syncthreads();
        if (t >= k0 - 16) {                 // rows < k0-16 are never consumed
#pragma unroll
            for (int kg = 0; kg < 4; kg++)
                *(float4*)&Ts[t * 40 + kg * 8] = *(const float4*)(Tm + t * 256 + k0 + kg * 8);
        }
        *(float4*)&Hs[scol * 40 + skg * 8] = *(const float4*)(hcol + k0 + skg * 8);
        __syncthreads();
        if (k0 <= w * 64 + 63) {
            f16x8 bf[4];
#pragma unroll
            for (int nb = 0; nb < 4; nb++) bf[nb] = *(f16x8*)&Hs[(nb * 16 + ln) * 40 + qd * 8];
#pragma unroll
            for (int a = 0; a < 4; a++) {
                if (k0 <= w * 64 + a * 16 + 15) {
                    f16x8 af = *(f16x8*)&Ts[(w * 64 + a * 16 + ln) * 40 + qd * 8];
#pragma unroll
                    for (int nb = 0; nb < 4; nb++)
                        acc[a][nb] = __builtin_amdgcn_mfma_f32_16x16x32_f16(af, bf[nb], acc[a][nb], 0, 0, 0);
                }
            }
        }
    }
    // ---- U @ S ----
    for (int k0 = 0; k0 < 64; k0 += 32) {
        __syncthreads();
#pragma unroll
        for (int kg = 0; kg < 4; kg++)
            *(float4*)&Ts[t * 40 + kg * 8] = *(const float4*)(Um + t * 64 + k0 + kg * 8);
        *(float4*)&Hs[scol * 40 + skg * 8] = *(const float4*)(sscol + k0 + skg * 8);
        __syncthreads();
        f16x8 bf[4];
#pragma unroll
        for (int nb = 0; nb < 4; nb++) bf[nb] = *(f16x8*)&Hs[(nb * 16 + ln) * 40 + qd * 8];
#pragma unroll
        for (int a = 0; a < 4; a++) {
            f16x8 af = *(f16x8*)&Ts[(w * 64 + a * 16 + ln) * 40 + qd * 8];
#pragma unroll
            for (int nb = 0; nb < 4; nb++)
                acc[a][nb] = __builtin_amdgcn_mfma_f32_16x16x32_f16(af, bf[nb], acc[a][nb], 0, 0, 0);
        }
    }
    // ---- epilogue: transpose through LDS, write y1 f16 [b][ch][l] in place ----
    int ocol = t >> 2, ojg = t & 3;
    int ocolg = ntile * 64 + ocol;
    f16* ybase = y1 + ((size_t)(ocolg >> 6) * 64 + ch) * 16384 + (size_t)(ocolg & 63) * 256;
    for (int hf = 0; hf < 2; hf++) {
        __syncthreads();
        if ((w >> 1) == hf) {
            int jl0 = (w & 1) * 64;
#pragma unroll
            for (int a = 0; a < 4; a++)
#pragma unroll
                for (int nb = 0; nb < 4; nb++)
#pragma unroll
                    for (int r = 0; r < 4; r++)
                        Ys[(nb * 16 + ln) * 136 + jl0 + a * 16 + qd * 4 + r] = (f16)acc[a][nb][r];
        }
        __syncthreads();
#pragma unroll
        for (int i = 0; i < 4; i++)
            *(float4*)(ybase + hf * 128 + ojg * 32 + i * 8) =
                *(const float4*)&Ys[ocol * 136 + ojg * 32 + i * 8];
    }
}

// ---------------------------------------------------------------------------
// K5c: reduce 1024 per-block BN partials -> mean, 1/sqrt(var+eps) per channel.
// grid 64 (one block per channel).
// ---------------------------------------------------------------------------
__global__ __launch_bounds__(256) void k5c_bnfin(float* __restrict__ ws) {
    int ch = blockIdx.x;
    int t = threadIdx.x;
    const float* part = ws + OFF_P;
    float s = 0.0f, ss = 0.0f;
#pragma unroll
    for (int i = 0; i < 4; i++) {
        int pb = t + i * 256;
        s  += part[(size_t)pb * 128 + ch];
        ss += part[(size_t)pb * 128 + 64 + ch];
    }
    for (int off = 32; off; off >>= 1) {
        s += __shfl_xor(s, off);
        ss += __shfl_xor(ss, off);
    }
    __shared__ float as_[4], ass_[4];
    int wv = t >> 6;
    if ((t & 63) == 0) { as_[wv] = s; ass_[wv] = ss; }
    __syncthreads();
    if (t == 0) {
        float S = as_[0] + as_[1] + as_[2] + as_[3];
        float SS = ass_[0] + ass_[1] + ass_[2] + ass_[3];
        float cnt = (float)BL;
        float mean = S / cnt;
        float var = SS / cnt - mean * mean;
        ws[OFF_BNF + ch] = mean;
        ws[OFF_BNF + 64 + ch] = 1.0f / sqrtf(var + 1e-5f);
    }
}

// ---------------------------------------------------------------------------
// K6M (MFMA-fused final): recomputes y2 = out_w @ y1 + out_b with the
// bit-identical MFMA sequence as k_cm2s, then applies BN + FiLM + PReLU +
// depthwise residual in registers and writes out directly.
// ---------------------------------------------------------------------------
__global__ __launch_bounds__(256) void k6m(const f16* __restrict__ y1,
                                           const float* __restrict__ W,
                                           const float* __restrict__ bias,
                                           const float* __restrict__ x,
                                           const float* __restrict__ ws,
                                           const float* __restrict__ a2p,
                                           const float* __restrict__ res_w,
                                           float* __restrict__ out) {
    int t = threadIdx.x, bi = blockIdx.x;
    int b = bi >> 6;
    int wv = t >> 6, lane = t & 63;
    int qd = lane >> 4, ln = lane & 15;
    int colw = ((bi & 63) << 8) + wv * 64;
    const f16* yb = y1 + (size_t)b * HH * LL;
    f32x4 acc[4][4];
#pragma unroll
    for (int a = 0; a < 4; a++)
#pragma unroll
        for (int nb = 0; nb < 4; nb++) acc[a][nb] = (f32x4)0.0f;
#pragma unroll
    for (int ks = 0; ks < 2; ks++) {
        f16x8 whi[4], wlo[4];
#pragma unroll
        for (int a = 0; a < 4; a++) {
            const float* wp = W + (size_t)(a * 16 + ln) * 64 + ks * 32 + qd * 8;
#pragma unroll
            for (int j = 0; j < 8; j++) {
                float f = wp[j];
                f16 hv = (f16)f;
                whi[a][j] = hv;
                wlo[a][j] = (f16)(f - (float)hv);
            }
        }
        f16x8 bf[4];
#pragma unroll
        for (int nb = 0; nb < 4; nb++) {
            const f16* yp = yb + (size_t)(ks * 32 + qd * 8) * LL + colw + nb * 16 + ln;
#pragma unroll
            for (int j = 0; j < 8; j++)
                bf[nb][j] = yp[(size_t)j * LL];
        }
#pragma unroll
        for (int a = 0; a < 4; a++)
#pragma unroll
            for (int nb = 0; nb < 4; nb++)
                acc[a][nb] = __builtin_amdgcn_mfma_f32_16x16x32_f16(whi[a], bf[nb], acc[a][nb], 0, 0, 0);
#pragma unroll
        for (int a = 0; a < 4; a++)
#pragma unroll
            for (int nb = 0; nb < 4; nb++)
                acc[a][nb] = __builtin_amdgcn_mfma_f32_16x16x32_f16(wlo[a], bf[nb], acc[a][nb], 0, 0, 0);
    }
    float a2 = *a2p;
    const float* xb = x + (size_t)b * HH * LL;
    float* ob = out + (size_t)b * HH * LL;
#pragma unroll
    for (int a = 0; a < 4; a++)
#pragma unroll
        for (int r = 0; r < 4; r++) {
            int g = a * 16 + qd * 4 + r;
            float bb = bias[g];
            float gamma = ws[OFF_GB + b * 128 + g];
            float beta  = ws[OFF_GB + b * 128 + 64 + g];
            float mean = ws[OFF_BNF + g];
            float inv  = ws[OFF_BNF + 64 + g];
            float scale = gamma * inv;
            float shift = beta - scale * mean;
            float rw = res_w[g];
            const float* xp = xb + (size_t)g * LL + colw + ln;
            float* op = ob + (size_t)g * LL + colw + ln;
#pragma unroll
            for (int nb = 0; nb < 4; nb++) {
                float v = acc[a][nb][r] + bb;       // y2 (bit-identical to cm2s)
                v = fmaf(scale, v, shift);
                v = (v >= 0.0f) ? v : a2 * v;
                op[nb * 16] = fmaf(rw, xp[nb * 16], v);
            }
        }
}

// ---------------------------------------------------------------------------
extern "C" void kernel_launch(void* const* d_in, const int* in_sizes, int n_in,
                              void* d_out, int out_size, void* d_ws, size_t ws_size,
                              hipStream_t stream) {
    const float* x        = (const float*)d_in[0];
    const float* cond     = (const float*)d_in[1];
    const float* linear_w = (const float*)d_in[2];
    const float* linear_b = (const float*)d_in[3];
    const float* prelu1_a = (const float*)d_in[4];
    const float* log_dt   = (const float*)d_in[5];
    const float* log_A    = (const float*)d_in[6];
    const float* A_imag   = (const float*)d_in[7];
    const float* C_re     = (const float*)d_in[8];
    const float* C_im     = (const float*)d_in[9];
    const float* Dskip    = (const float*)d_in[10];
    const float* out_w    = (const float*)d_in[11];
    const float* out_b    = (const float*)d_in[12];
    const float* film_w   = (const float*)d_in[13];
    const float* film_b   = (const float*)d_in[14];
    const float* prelu2_a = (const float*)d_in[15];
    const float* res_w    = (const float*)d_in[16];
    float* ws  = (float*)d_ws;
    float* out = (float*)d_out;
    f16* y1   = (f16*)(ws + OFF_H);   // y1 aliases h (overwritten in place)

    hipLaunchKernelGGL(m0_setup, dim3(80), dim3(256), 0, stream,
                       log_dt, log_A, A_imag, C_re, C_im, cond, film_w, film_b,
                       Dskip, ws);
    hipLaunchKernelGGL(m1_build_cm1, dim3(2048), dim3(256), 0, stream,
                       log_dt, log_A, A_imag, x, linear_w, linear_b, prelu1_a, ws);
    hipLaunchKernelGGL(gemmA, dim3(256), dim3(256), 0, stream, ws);
    hipLaunchKernelGGL(k3_scan, dim3(128), dim3(256), 0, stream, ws);
    hipLaunchKernelGGL(gemmMain, dim3(1024), dim3(256), 0, stream, ws);
    hipLaunchKernelGGL(k_cm2s, dim3(1024), dim3(256), 0, stream,
                       y1, out_w, out_b, ws);
    hipLaunchKernelGGL(k5c_bnfin, dim3(64), dim3(256), 0, stream, ws);
    hipLaunchKernelGGL(k6m, dim3(1024), dim3(256), 0, stream,
                       y1, out_w, out_b, x, ws, prelu2_a, res_w, out);
}